// Round 4
// baseline (1069.395 us; speedup 1.0000x reference)
//
#include <hip/hip_runtime.h>
#include <hip/hip_bf16.h>
#include <cstdint>

#define N_NODES 50000
#define N_EDGES 800000
#define DIM     128
#define NLAYERS 4

#define SCAN_BLK 256
#define NB ((N_NODES + SCAN_BLK - 1) / SCAN_BLK)   // 196 scan blocks

// ---------------- CSR build ----------------

__global__ __launch_bounds__(256) void zero_kernel(int* __restrict__ p, int n) {
    int i = blockIdx.x * blockDim.x + threadIdx.x;
    if (i < n) p[i] = 0;
}

__global__ __launch_bounds__(256) void count_kernel(const int* __restrict__ dst,
                                                    int* __restrict__ cnt) {
    int e = blockIdx.x * blockDim.x + threadIdx.x;
    if (e < N_EDGES) atomicAdd(&cnt[dst[e]], 1);
}

// per-block exclusive scan of cnt -> off (partial), block totals -> bsum
__global__ __launch_bounds__(SCAN_BLK) void scanA(const int* __restrict__ cnt,
                                                  int* __restrict__ off,
                                                  int* __restrict__ bsum) {
    __shared__ int s[SCAN_BLK];
    const int t = threadIdx.x;
    const int i = blockIdx.x * SCAN_BLK + t;
    int v = (i < N_NODES) ? cnt[i] : 0;
    s[t] = v;
    __syncthreads();
    for (int d = 1; d < SCAN_BLK; d <<= 1) {
        int add = (t >= d) ? s[t - d] : 0;
        __syncthreads();
        s[t] += add;
        __syncthreads();
    }
    if (i < N_NODES) off[i] = s[t] - v;        // exclusive within block
    if (t == SCAN_BLK - 1) bsum[blockIdx.x] = s[t];
}

// exclusive scan of block sums in place (NB <= 256)
__global__ __launch_bounds__(SCAN_BLK) void scanB(int* __restrict__ bsum) {
    __shared__ int s[SCAN_BLK];
    const int t = threadIdx.x;
    int v = (t < NB) ? bsum[t] : 0;
    s[t] = v;
    __syncthreads();
    for (int d = 1; d < SCAN_BLK; d <<= 1) {
        int add = (t >= d) ? s[t - d] : 0;
        __syncthreads();
        s[t] += add;
        __syncthreads();
    }
    if (t < NB) bsum[t] = s[t] - v;            // exclusive
}

__global__ __launch_bounds__(SCAN_BLK) void scanC(int* __restrict__ off,
                                                  const int* __restrict__ bsum,
                                                  int* __restrict__ cur) {
    const int i = blockIdx.x * SCAN_BLK + threadIdx.x;
    if (i < N_NODES) {
        int o = off[i] + bsum[blockIdx.x];
        off[i] = o;
        cur[i] = o;
    }
    if (i == 0) off[N_NODES] = N_EDGES;
}

__global__ __launch_bounds__(256) void scatter_kernel(const int* __restrict__ src,
                                                      const int* __restrict__ dst,
                                                      int* __restrict__ cur,
                                                      int* __restrict__ csr) {
    int e = blockIdx.x * blockDim.x + threadIdx.x;
    if (e < N_EDGES) {
        int d = dst[e];
        int pos = atomicAdd(&cur[d], 1);
        csr[pos] = src[e];
    }
}

// ---------------- fused GIN layer: agg -> GEMM1+ReLU -> GEMM2 ----------------
// RT rows per block, 256 threads. Tiles live in LDS; x read once, written once.

#define RT 32
#define LDW 132   // padded row stride (floats): breaks bank aliasing, 16B multiple

__global__ __launch_bounds__(256) void gin_layer(
    const float* __restrict__ xin, const int* __restrict__ off,
    const int* __restrict__ csr,
    const float* __restrict__ W1, const float* __restrict__ b1,
    const float* __restrict__ W2, const float* __restrict__ b2,
    float* __restrict__ xout)
{
    __shared__ float sA[RT][LDW];
    __shared__ float sH[RT][LDW];
    const int tid  = threadIdx.x;
    const int base = blockIdx.x * RT;

    // ---- phase 1: aggregation into sA ----
    {
        const int d = tid & (DIM - 1);   // 0..127
        const int q = tid >> 7;          // 0..1
        for (int rr = q; rr < RT; rr += 2) {
            const int node = base + rr;
            float acc = 0.f;
            if (node < N_NODES) {
                acc = xin[node * DIM + d];
                const int k0 = off[node], k1 = off[node + 1];
                int k = k0;
                // 4-way unrolled gather: batch independent loads so the
                // compiler issues 4 idx loads + 4 row loads before waiting,
                // instead of a dependent load->load chain per neighbor.
                for (; k + 4 <= k1; k += 4) {
                    const int i0 = csr[k + 0];
                    const int i1 = csr[k + 1];
                    const int i2 = csr[k + 2];
                    const int i3 = csr[k + 3];
                    const float v0 = xin[i0 * DIM + d];
                    const float v1 = xin[i1 * DIM + d];
                    const float v2 = xin[i2 * DIM + d];
                    const float v3 = xin[i3 * DIM + d];
                    acc += v0 + v1 + v2 + v3;
                }
                for (; k < k1; ++k) {
                    acc += xin[csr[k] * DIM + d];
                }
            }
            sA[rr][d] = acc;
        }
    }
    __syncthreads();

    const int tc = tid & 31;   // col group: cols tc*4 .. tc*4+3
    const int tr = tid >> 5;   // row group: rows tr*4 .. tr*4+3

    // ---- phase 2: sH = relu(sA @ W1 + b1) ----
    {
        float acc[4][4] = {};
        const float4* Wv = reinterpret_cast<const float4*>(W1);
        #pragma unroll 4
        for (int k4 = 0; k4 < DIM / 4; ++k4) {
            float4 w[4];
            #pragma unroll
            for (int j = 0; j < 4; ++j) w[j] = Wv[(k4 * 4 + j) * 32 + tc];
            #pragma unroll
            for (int i = 0; i < 4; ++i) {
                const float4 a = *reinterpret_cast<const float4*>(&sA[tr * 4 + i][k4 * 4]);
                acc[i][0] += a.x * w[0].x + a.y * w[1].x + a.z * w[2].x + a.w * w[3].x;
                acc[i][1] += a.x * w[0].y + a.y * w[1].y + a.z * w[2].y + a.w * w[3].y;
                acc[i][2] += a.x * w[0].z + a.y * w[1].z + a.z * w[2].z + a.w * w[3].z;
                acc[i][3] += a.x * w[0].w + a.y * w[1].w + a.z * w[2].w + a.w * w[3].w;
            }
        }
        const float4 b = reinterpret_cast<const float4*>(b1)[tc];
        #pragma unroll
        for (int i = 0; i < 4; ++i) {
            float4 h;
            h.x = fmaxf(acc[i][0] + b.x, 0.f);
            h.y = fmaxf(acc[i][1] + b.y, 0.f);
            h.z = fmaxf(acc[i][2] + b.z, 0.f);
            h.w = fmaxf(acc[i][3] + b.w, 0.f);
            *reinterpret_cast<float4*>(&sH[tr * 4 + i][tc * 4]) = h;
        }
    }
    __syncthreads();

    // ---- phase 3: xout = sH @ W2 + b2 ----
    {
        float acc[4][4] = {};
        const float4* Wv = reinterpret_cast<const float4*>(W2);
        #pragma unroll 4
        for (int k4 = 0; k4 < DIM / 4; ++k4) {
            float4 w[4];
            #pragma unroll
            for (int j = 0; j < 4; ++j) w[j] = Wv[(k4 * 4 + j) * 32 + tc];
            #pragma unroll
            for (int i = 0; i < 4; ++i) {
                const float4 a = *reinterpret_cast<const float4*>(&sH[tr * 4 + i][k4 * 4]);
                acc[i][0] += a.x * w[0].x + a.y * w[1].x + a.z * w[2].x + a.w * w[3].x;
                acc[i][1] += a.x * w[0].y + a.y * w[1].y + a.z * w[2].y + a.w * w[3].y;
                acc[i][2] += a.x * w[0].z + a.y * w[1].z + a.z * w[2].z + a.w * w[3].z;
                acc[i][3] += a.x * w[0].w + a.y * w[1].w + a.z * w[2].w + a.w * w[3].w;
            }
        }
        const float4 b = reinterpret_cast<const float4*>(b2)[tc];
        #pragma unroll
        for (int i = 0; i < 4; ++i) {
            const int node = base + tr * 4 + i;
            if (node < N_NODES) {
                float4 o;
                o.x = acc[i][0] + b.x;
                o.y = acc[i][1] + b.y;
                o.z = acc[i][2] + b.z;
                o.w = acc[i][3] + b.w;
                reinterpret_cast<float4*>(xout + node * DIM)[tc] = o;
            }
        }
    }
}

// ---------------- launch ----------------

extern "C" void kernel_launch(void* const* d_in, const int* in_sizes, int n_in,
                              void* d_out, int out_size, void* d_ws, size_t ws_size,
                              hipStream_t stream) {
    const float* x  = (const float*)d_in[0];
    const int*   ei = (const int*)d_in[1];     // [2][N_EDGES]: src row then dst row
    // d_in[2] = batch (unused)
    const float* W1 = (const float*)d_in[3];
    const float* b1 = (const float*)d_in[4];
    const float* W2 = (const float*)d_in[5];
    const float* b2 = (const float*)d_in[6];
    float* out = (float*)d_out;

    const int* src = ei;
    const int* dst = ei + N_EDGES;

    // workspace layout: one ping-pong float buffer (d_out is the other),
    // then the CSR/scan int arrays. Total ≈ 25.6 MB + 3.8 MB.
    float* bufA = (float*)d_ws;                         // N_NODES*DIM floats
    int*   cnt  = (int*)(bufA + (size_t)N_NODES * DIM); // N_NODES
    int*   offs = cnt + N_NODES;                        // N_NODES+1
    int*   cur  = offs + N_NODES + 1;                   // N_NODES
    int*   bsum = cur + N_NODES;                        // 256
    int*   csr  = bsum + 256;                           // N_EDGES

    // --- build CSR (dst -> srcs) once per call ---
    // zero via kernel (not hipMemsetAsync) to keep graph capture trivially safe
    zero_kernel<<<NB, 256, 0, stream>>>(cnt, N_NODES);
    count_kernel<<<(N_EDGES + 255) / 256, 256, 0, stream>>>(dst, cnt);
    scanA<<<NB, SCAN_BLK, 0, stream>>>(cnt, offs, bsum);
    scanB<<<1, SCAN_BLK, 0, stream>>>(bsum);
    scanC<<<NB, SCAN_BLK, 0, stream>>>(offs, bsum, cur);
    scatter_kernel<<<(N_EDGES + 255) / 256, 256, 0, stream>>>(src, dst, cur, csr);

    const int nblk = (N_NODES + RT - 1) / RT;
    // layer 0: x -> bufA
    gin_layer<<<nblk, 256, 0, stream>>>(x,    offs, csr, W1 + 0 * DIM * DIM, b1 + 0 * DIM,
                                        W2 + 0 * DIM * DIM, b2 + 0 * DIM, bufA);
    // layer 1: bufA -> out (d_out doubles as ping-pong buffer)
    gin_layer<<<nblk, 256, 0, stream>>>(bufA, offs, csr, W1 + 1 * DIM * DIM, b1 + 1 * DIM,
                                        W2 + 1 * DIM * DIM, b2 + 1 * DIM, out);
    // layer 2: out -> bufA
    gin_layer<<<nblk, 256, 0, stream>>>(out,  offs, csr, W1 + 2 * DIM * DIM, b1 + 2 * DIM,
                                        W2 + 2 * DIM * DIM, b2 + 2 * DIM, bufA);
    // layer 3: bufA -> out
    gin_layer<<<nblk, 256, 0, stream>>>(bufA, offs, csr, W1 + 3 * DIM * DIM, b1 + 3 * DIM,
                                        W2 + 3 * DIM * DIM, b2 + 3 * DIM, out);
}

// Round 5
// 905.620 us; speedup vs baseline: 1.1808x; 1.1808x over previous
//
#include <hip/hip_runtime.h>
#include <hip/hip_bf16.h>
#include <cstdint>

#define N_NODES 50000
#define N_EDGES 800000
#define DIM     128
#define NLAYERS 4

#define SCAN_BLK 256
#define NB ((N_NODES + SCAN_BLK - 1) / SCAN_BLK)   // 196 scan blocks

// ---------------- CSR build ----------------

__global__ __launch_bounds__(256) void zero_kernel(int* __restrict__ p, int n) {
    int i = blockIdx.x * blockDim.x + threadIdx.x;
    if (i < n) p[i] = 0;
}

__global__ __launch_bounds__(256) void count_kernel(const int* __restrict__ dst,
                                                    int* __restrict__ cnt) {
    int e = blockIdx.x * blockDim.x + threadIdx.x;
    if (e < N_EDGES) atomicAdd(&cnt[dst[e]], 1);
}

// per-block exclusive scan of cnt -> off (partial), block totals -> bsum
__global__ __launch_bounds__(SCAN_BLK) void scanA(const int* __restrict__ cnt,
                                                  int* __restrict__ off,
                                                  int* __restrict__ bsum) {
    __shared__ int s[SCAN_BLK];
    const int t = threadIdx.x;
    const int i = blockIdx.x * SCAN_BLK + t;
    int v = (i < N_NODES) ? cnt[i] : 0;
    s[t] = v;
    __syncthreads();
    for (int d = 1; d < SCAN_BLK; d <<= 1) {
        int add = (t >= d) ? s[t - d] : 0;
        __syncthreads();
        s[t] += add;
        __syncthreads();
    }
    if (i < N_NODES) off[i] = s[t] - v;        // exclusive within block
    if (t == SCAN_BLK - 1) bsum[blockIdx.x] = s[t];
}

// exclusive scan of block sums in place (NB <= 256)
__global__ __launch_bounds__(SCAN_BLK) void scanB(int* __restrict__ bsum) {
    __shared__ int s[SCAN_BLK];
    const int t = threadIdx.x;
    int v = (t < NB) ? bsum[t] : 0;
    s[t] = v;
    __syncthreads();
    for (int d = 1; d < SCAN_BLK; d <<= 1) {
        int add = (t >= d) ? s[t - d] : 0;
        __syncthreads();
        s[t] += add;
        __syncthreads();
    }
    if (t < NB) bsum[t] = s[t] - v;            // exclusive
}

__global__ __launch_bounds__(SCAN_BLK) void scanC(int* __restrict__ off,
                                                  const int* __restrict__ bsum,
                                                  int* __restrict__ cur) {
    const int i = blockIdx.x * SCAN_BLK + threadIdx.x;
    if (i < N_NODES) {
        int o = off[i] + bsum[blockIdx.x];
        off[i] = o;
        cur[i] = o;
    }
    if (i == 0) off[N_NODES] = N_EDGES;
}

__global__ __launch_bounds__(256) void scatter_kernel(const int* __restrict__ src,
                                                      const int* __restrict__ dst,
                                                      int* __restrict__ cur,
                                                      int* __restrict__ csr) {
    int e = blockIdx.x * blockDim.x + threadIdx.x;
    if (e < N_EDGES) {
        int d = dst[e];
        int pos = atomicAdd(&cur[d], 1);
        csr[pos] = src[e];
    }
}

// ---------------- fused GIN layer: agg -> GEMM1+ReLU -> GEMM2 ----------------
// RT rows per block, 256 threads. Index slice staged in LDS (kills the
// global->global dependent chain); H round-trips through registers so sA is
// reused and LDS stays ~21 KB -> 7 blocks/CU for latency hiding.

#define RT 32
#define LDW 132    // padded row stride (floats)
#define MAXE 1024  // staged-index capacity (block avg ~512); fallback if exceeded

__global__ __launch_bounds__(256) void gin_layer(
    const float* __restrict__ xin, const int* __restrict__ off,
    const int* __restrict__ csr,
    const float* __restrict__ W1, const float* __restrict__ b1,
    const float* __restrict__ W2, const float* __restrict__ b2,
    float* __restrict__ xout)
{
    __shared__ float sA[RT][LDW];
    __shared__ int   sIdx[MAXE];
    __shared__ int   sOff[RT + 1];
    const int tid  = threadIdx.x;
    const int base = blockIdx.x * RT;
    const int rtop = min(RT, N_NODES - base);   // valid rows in this block

    if (tid <= rtop) sOff[tid] = off[base + tid];
    __syncthreads();

    const int e0 = sOff[0];
    const int nE = sOff[rtop] - e0;
    const bool staged = (nE <= MAXE);
    if (staged) {
        for (int i = tid; i < nE; i += 256) sIdx[i] = csr[e0 + i];
    }
    __syncthreads();

    // ---- phase 1: aggregation into sA ----
    {
        const int d = tid & (DIM - 1);   // 0..127
        const int q = tid >> 7;          // 0..1
        for (int rr = q; rr < rtop; rr += 2) {
            float acc = xin[(base + rr) * DIM + d];   // self (eps=0)
            const int k0 = sOff[rr] - e0, k1 = sOff[rr + 1] - e0;
            int k = k0;
            if (staged) {
                // 8 independent row loads in flight; index reads are LDS-fast
                for (; k + 8 <= k1; k += 8) {
                    int id[8];
                    float v[8];
                    #pragma unroll
                    for (int j = 0; j < 8; ++j) id[j] = sIdx[k + j];
                    #pragma unroll
                    for (int j = 0; j < 8; ++j) v[j] = xin[id[j] * DIM + d];
                    acc += ((v[0] + v[1]) + (v[2] + v[3])) +
                           ((v[4] + v[5]) + (v[6] + v[7]));
                }
                for (; k < k1; ++k) acc += xin[sIdx[k] * DIM + d];
            } else {
                // overflow fallback (statistically never at avg degree 16)
                for (; k < k1; ++k) acc += xin[csr[e0 + k] * DIM + d];
            }
            sA[rr][d] = acc;
        }
    }
    __syncthreads();

    const int tc = tid & 31;   // col group: cols tc*4 .. tc*4+3
    const int tr = tid >> 5;   // row group: rows tr*4 .. tr*4+3

    // ---- phase 2: acc = relu(sA @ W1 + b1) (held in registers) ----
    float acc[4][4] = {};
    {
        const float4* Wv = reinterpret_cast<const float4*>(W1);
        #pragma unroll 4
        for (int k4 = 0; k4 < DIM / 4; ++k4) {
            float4 w[4];
            #pragma unroll
            for (int j = 0; j < 4; ++j) w[j] = Wv[(k4 * 4 + j) * 32 + tc];
            #pragma unroll
            for (int i = 0; i < 4; ++i) {
                const float4 a = *reinterpret_cast<const float4*>(&sA[tr * 4 + i][k4 * 4]);
                acc[i][0] += a.x * w[0].x + a.y * w[1].x + a.z * w[2].x + a.w * w[3].x;
                acc[i][1] += a.x * w[0].y + a.y * w[1].y + a.z * w[2].y + a.w * w[3].y;
                acc[i][2] += a.x * w[0].z + a.y * w[1].z + a.z * w[2].z + a.w * w[3].z;
                acc[i][3] += a.x * w[0].w + a.y * w[1].w + a.z * w[2].w + a.w * w[3].w;
            }
        }
        const float4 b = reinterpret_cast<const float4*>(b1)[tc];
        #pragma unroll
        for (int i = 0; i < 4; ++i) {
            acc[i][0] = fmaxf(acc[i][0] + b.x, 0.f);
            acc[i][1] = fmaxf(acc[i][1] + b.y, 0.f);
            acc[i][2] = fmaxf(acc[i][2] + b.z, 0.f);
            acc[i][3] = fmaxf(acc[i][3] + b.w, 0.f);
        }
    }
    __syncthreads();   // all reads of sA complete

    // write H back into sA (reuse)
    #pragma unroll
    for (int i = 0; i < 4; ++i) {
        float4 h;
        h.x = acc[i][0]; h.y = acc[i][1]; h.z = acc[i][2]; h.w = acc[i][3];
        *reinterpret_cast<float4*>(&sA[tr * 4 + i][tc * 4]) = h;
    }
    __syncthreads();

    // ---- phase 3: xout = sA(=H) @ W2 + b2 ----
    {
        float acc2[4][4] = {};
        const float4* Wv = reinterpret_cast<const float4*>(W2);
        #pragma unroll 4
        for (int k4 = 0; k4 < DIM / 4; ++k4) {
            float4 w[4];
            #pragma unroll
            for (int j = 0; j < 4; ++j) w[j] = Wv[(k4 * 4 + j) * 32 + tc];
            #pragma unroll
            for (int i = 0; i < 4; ++i) {
                const float4 a = *reinterpret_cast<const float4*>(&sA[tr * 4 + i][k4 * 4]);
                acc2[i][0] += a.x * w[0].x + a.y * w[1].x + a.z * w[2].x + a.w * w[3].x;
                acc2[i][1] += a.x * w[0].y + a.y * w[1].y + a.z * w[2].y + a.w * w[3].y;
                acc2[i][2] += a.x * w[0].z + a.y * w[1].z + a.z * w[2].z + a.w * w[3].z;
                acc2[i][3] += a.x * w[0].w + a.y * w[1].w + a.z * w[2].w + a.w * w[3].w;
            }
        }
        const float4 b = reinterpret_cast<const float4*>(b2)[tc];
        #pragma unroll
        for (int i = 0; i < 4; ++i) {
            const int node = base + tr * 4 + i;
            if (node < N_NODES) {
                float4 o;
                o.x = acc2[i][0] + b.x;
                o.y = acc2[i][1] + b.y;
                o.z = acc2[i][2] + b.z;
                o.w = acc2[i][3] + b.w;
                reinterpret_cast<float4*>(xout + node * DIM)[tc] = o;
            }
        }
    }
}

// ---------------- launch ----------------

extern "C" void kernel_launch(void* const* d_in, const int* in_sizes, int n_in,
                              void* d_out, int out_size, void* d_ws, size_t ws_size,
                              hipStream_t stream) {
    const float* x  = (const float*)d_in[0];
    const int*   ei = (const int*)d_in[1];     // [2][N_EDGES]: src row then dst row
    // d_in[2] = batch (unused)
    const float* W1 = (const float*)d_in[3];
    const float* b1 = (const float*)d_in[4];
    const float* W2 = (const float*)d_in[5];
    const float* b2 = (const float*)d_in[6];
    float* out = (float*)d_out;

    const int* src = ei;
    const int* dst = ei + N_EDGES;

    // workspace layout: one ping-pong float buffer (d_out is the other),
    // then the CSR/scan int arrays. Total ≈ 25.6 MB + 3.8 MB.
    float* bufA = (float*)d_ws;                         // N_NODES*DIM floats
    int*   cnt  = (int*)(bufA + (size_t)N_NODES * DIM); // N_NODES
    int*   offs = cnt + N_NODES;                        // N_NODES+1
    int*   cur  = offs + N_NODES + 1;                   // N_NODES
    int*   bsum = cur + N_NODES;                        // 256
    int*   csr  = bsum + 256;                           // N_EDGES

    // --- build CSR (dst -> srcs) once per call ---
    zero_kernel<<<NB, 256, 0, stream>>>(cnt, N_NODES);
    count_kernel<<<(N_EDGES + 255) / 256, 256, 0, stream>>>(dst, cnt);
    scanA<<<NB, SCAN_BLK, 0, stream>>>(cnt, offs, bsum);
    scanB<<<1, SCAN_BLK, 0, stream>>>(bsum);
    scanC<<<NB, SCAN_BLK, 0, stream>>>(offs, bsum, cur);
    scatter_kernel<<<(N_EDGES + 255) / 256, 256, 0, stream>>>(src, dst, cur, csr);

    const int nblk = (N_NODES + RT - 1) / RT;
    // layer 0: x -> bufA
    gin_layer<<<nblk, 256, 0, stream>>>(x,    offs, csr, W1 + 0 * DIM * DIM, b1 + 0 * DIM,
                                        W2 + 0 * DIM * DIM, b2 + 0 * DIM, bufA);
    // layer 1: bufA -> out (d_out doubles as ping-pong buffer)
    gin_layer<<<nblk, 256, 0, stream>>>(bufA, offs, csr, W1 + 1 * DIM * DIM, b1 + 1 * DIM,
                                        W2 + 1 * DIM * DIM, b2 + 1 * DIM, out);
    // layer 2: out -> bufA
    gin_layer<<<nblk, 256, 0, stream>>>(out,  offs, csr, W1 + 2 * DIM * DIM, b1 + 2 * DIM,
                                        W2 + 2 * DIM * DIM, b2 + 2 * DIM, bufA);
    // layer 3: bufA -> out
    gin_layer<<<nblk, 256, 0, stream>>>(bufA, offs, csr, W1 + 3 * DIM * DIM, b1 + 3 * DIM,
                                        W2 + 3 * DIM * DIM, b2 + 3 * DIM, out);
}

// Round 7
// 763.959 us; speedup vs baseline: 1.3998x; 1.1854x over previous
//
#include <hip/hip_runtime.h>
#include <hip/hip_bf16.h>
#include <cstdint>

#define N_NODES 50000
#define N_EDGES 800000
#define DIM     128
#define NLAYERS 4

#define SCAN_BLK 256
#define NB ((N_NODES + SCAN_BLK - 1) / SCAN_BLK)   // 196 scan blocks

// ---------------- CSR build ----------------

__global__ __launch_bounds__(256) void zero_kernel(int* __restrict__ p, int n) {
    int i = blockIdx.x * blockDim.x + threadIdx.x;
    if (i < n) p[i] = 0;
}

__global__ __launch_bounds__(256) void count_kernel(const int* __restrict__ dst,
                                                    int* __restrict__ cnt) {
    int e = blockIdx.x * blockDim.x + threadIdx.x;
    if (e < N_EDGES) atomicAdd(&cnt[dst[e]], 1);
}

// per-block exclusive scan of cnt -> off (partial), block totals -> bsum
__global__ __launch_bounds__(SCAN_BLK) void scanA(const int* __restrict__ cnt,
                                                  int* __restrict__ off,
                                                  int* __restrict__ bsum) {
    __shared__ int s[SCAN_BLK];
    const int t = threadIdx.x;
    const int i = blockIdx.x * SCAN_BLK + t;
    int v = (i < N_NODES) ? cnt[i] : 0;
    s[t] = v;
    __syncthreads();
    for (int d = 1; d < SCAN_BLK; d <<= 1) {
        int add = (t >= d) ? s[t - d] : 0;
        __syncthreads();
        s[t] += add;
        __syncthreads();
    }
    if (i < N_NODES) off[i] = s[t] - v;        // exclusive within block
    if (t == SCAN_BLK - 1) bsum[blockIdx.x] = s[t];
}

// exclusive scan of block sums in place (NB <= 256)
__global__ __launch_bounds__(SCAN_BLK) void scanB(int* __restrict__ bsum) {
    __shared__ int s[SCAN_BLK];
    const int t = threadIdx.x;
    int v = (t < NB) ? bsum[t] : 0;
    s[t] = v;
    __syncthreads();
    for (int d = 1; d < SCAN_BLK; d <<= 1) {
        int add = (t >= d) ? s[t - d] : 0;
        __syncthreads();
        s[t] += add;
        __syncthreads();
    }
    if (t < NB) bsum[t] = s[t] - v;            // exclusive
}

__global__ __launch_bounds__(SCAN_BLK) void scanC(int* __restrict__ off,
                                                  const int* __restrict__ bsum,
                                                  int* __restrict__ cur) {
    const int i = blockIdx.x * SCAN_BLK + threadIdx.x;
    if (i < N_NODES) {
        int o = off[i] + bsum[blockIdx.x];
        off[i] = o;
        cur[i] = o;
    }
    if (i == 0) off[N_NODES] = N_EDGES;
}

__global__ __launch_bounds__(256) void scatter_kernel(const int* __restrict__ src,
                                                      const int* __restrict__ dst,
                                                      int* __restrict__ cur,
                                                      int* __restrict__ csr) {
    int e = blockIdx.x * blockDim.x + threadIdx.x;
    if (e < N_EDGES) {
        int d = dst[e];
        int pos = atomicAdd(&cur[d], 1);
        csr[pos] = src[e];
    }
}

// ---------------- fused GIN layer: agg -> GEMM1+ReLU -> GEMM2 ----------------
// RT rows per block, 256 threads. Gather is float4-per-lane: a 32-lane group
// loads one full 512B row per instruction, 8 rows in flight per group ->
// ~8KB outstanding per wave (vs 2KB scalar) to cover L2/L3 latency.

#define RT 32
#define LDW 132    // padded row stride (floats)
#define MAXE 1024  // staged-index capacity (block avg ~512; >22 sigma headroom)

__global__ __launch_bounds__(256) void gin_layer(
    const float* __restrict__ xin, const int* __restrict__ off,
    const int* __restrict__ csr,
    const float* __restrict__ W1, const float* __restrict__ b1,
    const float* __restrict__ W2, const float* __restrict__ b2,
    float* __restrict__ xout)
{
    __shared__ float sA[RT][LDW];
    __shared__ int   sIdx[MAXE];
    __shared__ int   sOff[RT + 1];
    const int tid  = threadIdx.x;
    const int base = blockIdx.x * RT;
    const int rtop = min(RT, N_NODES - base);   // valid rows in this block

    if (tid <= rtop) sOff[tid] = off[base + tid];
    __syncthreads();

    const int e0 = sOff[0];
    const int nE = sOff[rtop] - e0;
    const bool staged = (nE <= MAXE);
    if (staged) {
        for (int i = tid; i < nE; i += 256) sIdx[i] = csr[e0 + i];
    }
    __syncthreads();

    // ---- phase 1: float4 aggregation into sA ----
    {
        const int c = tid & 31;          // float4 column: floats 4c..4c+3
        const int g = tid >> 5;          // row group 0..7
        const float4* xin4 = reinterpret_cast<const float4*>(xin);
        #pragma unroll
        for (int it = 0; it < 4; ++it) {
            const int rr = g + it * 8;
            if (rr < rtop) {
                const int node = base + rr;
                float4 a = xin4[node * 32 + c];   // self (eps=0)
                const int k0 = sOff[rr] - e0, k1 = sOff[rr + 1] - e0;
                int k = k0;
                if (staged) {
                    for (; k + 8 <= k1; k += 8) {
                        int id[8];
                        #pragma unroll
                        for (int j = 0; j < 8; ++j) id[j] = sIdx[k + j];
                        float4 v0 = xin4[id[0] * 32 + c];
                        float4 v1 = xin4[id[1] * 32 + c];
                        float4 v2 = xin4[id[2] * 32 + c];
                        float4 v3 = xin4[id[3] * 32 + c];
                        float4 v4 = xin4[id[4] * 32 + c];
                        float4 v5 = xin4[id[5] * 32 + c];
                        float4 v6 = xin4[id[6] * 32 + c];
                        float4 v7 = xin4[id[7] * 32 + c];
                        a.x += ((v0.x + v1.x) + (v2.x + v3.x)) + ((v4.x + v5.x) + (v6.x + v7.x));
                        a.y += ((v0.y + v1.y) + (v2.y + v3.y)) + ((v4.y + v5.y) + (v6.y + v7.y));
                        a.z += ((v0.z + v1.z) + (v2.z + v3.z)) + ((v4.z + v5.z) + (v6.z + v7.z));
                        a.w += ((v0.w + v1.w) + (v2.w + v3.w)) + ((v4.w + v5.w) + (v6.w + v7.w));
                    }
                    for (; k < k1; ++k) {
                        float4 v = xin4[sIdx[k] * 32 + c];
                        a.x += v.x; a.y += v.y; a.z += v.z; a.w += v.w;
                    }
                } else {
                    for (; k < k1; ++k) {
                        float4 v = xin4[csr[e0 + k] * 32 + c];
                        a.x += v.x; a.y += v.y; a.z += v.z; a.w += v.w;
                    }
                }
                *reinterpret_cast<float4*>(&sA[rr][c * 4]) = a;
            }
        }
    }
    __syncthreads();

    const int tc = tid & 31;   // col group: cols tc*4 .. tc*4+3
    const int tr = tid >> 5;   // row group: rows tr*4 .. tr*4+3

    // ---- phase 2: acc = relu(sA @ W1 + b1) (held in registers) ----
    float acc[4][4] = {};
    {
        const float4* Wv = reinterpret_cast<const float4*>(W1);
        #pragma unroll 4
        for (int k4 = 0; k4 < DIM / 4; ++k4) {
            float4 w[4];
            #pragma unroll
            for (int j = 0; j < 4; ++j) w[j] = Wv[(k4 * 4 + j) * 32 + tc];
            #pragma unroll
            for (int i = 0; i < 4; ++i) {
                const float4 a = *reinterpret_cast<const float4*>(&sA[tr * 4 + i][k4 * 4]);
                acc[i][0] += a.x * w[0].x + a.y * w[1].x + a.z * w[2].x + a.w * w[3].x;
                acc[i][1] += a.x * w[0].y + a.y * w[1].y + a.z * w[2].y + a.w * w[3].y;
                acc[i][2] += a.x * w[0].z + a.y * w[1].z + a.z * w[2].z + a.w * w[3].z;
                acc[i][3] += a.x * w[0].w + a.y * w[1].w + a.z * w[2].w + a.w * w[3].w;
            }
        }
        const float4 b = reinterpret_cast<const float4*>(b1)[tc];
        #pragma unroll
        for (int i = 0; i < 4; ++i) {
            acc[i][0] = fmaxf(acc[i][0] + b.x, 0.f);
            acc[i][1] = fmaxf(acc[i][1] + b.y, 0.f);
            acc[i][2] = fmaxf(acc[i][2] + b.z, 0.f);
            acc[i][3] = fmaxf(acc[i][3] + b.w, 0.f);
        }
    }
    __syncthreads();   // all reads of sA complete

    // write H back into sA (reuse)
    #pragma unroll
    for (int i = 0; i < 4; ++i) {
        float4 h;
        h.x = acc[i][0]; h.y = acc[i][1]; h.z = acc[i][2]; h.w = acc[i][3];
        *reinterpret_cast<float4*>(&sA[tr * 4 + i][tc * 4]) = h;
    }
    __syncthreads();

    // ---- phase 3: xout = sA(=H) @ W2 + b2 ----
    {
        float acc2[4][4] = {};
        const float4* Wv = reinterpret_cast<const float4*>(W2);
        #pragma unroll 4
        for (int k4 = 0; k4 < DIM / 4; ++k4) {
            float4 w[4];
            #pragma unroll
            for (int j = 0; j < 4; ++j) w[j] = Wv[(k4 * 4 + j) * 32 + tc];
            #pragma unroll
            for (int i = 0; i < 4; ++i) {
                const float4 a = *reinterpret_cast<const float4*>(&sA[tr * 4 + i][k4 * 4]);
                acc2[i][0] += a.x * w[0].x + a.y * w[1].x + a.z * w[2].x + a.w * w[3].x;
                acc2[i][1] += a.x * w[0].y + a.y * w[1].y + a.z * w[2].y + a.w * w[3].y;
                acc2[i][2] += a.x * w[0].z + a.y * w[1].z + a.z * w[2].z + a.w * w[3].z;
                acc2[i][3] += a.x * w[0].w + a.y * w[1].w + a.z * w[2].w + a.w * w[3].w;
            }
        }
        const float4 b = reinterpret_cast<const float4*>(b2)[tc];
        #pragma unroll
        for (int i = 0; i < 4; ++i) {
            const int node = base + tr * 4 + i;
            if (node < N_NODES) {
                float4 o;
                o.x = acc2[i][0] + b.x;
                o.y = acc2[i][1] + b.y;
                o.z = acc2[i][2] + b.z;
                o.w = acc2[i][3] + b.w;
                reinterpret_cast<float4*>(xout + node * DIM)[tc] = o;
            }
        }
    }
}

// ---------------- launch ----------------

extern "C" void kernel_launch(void* const* d_in, const int* in_sizes, int n_in,
                              void* d_out, int out_size, void* d_ws, size_t ws_size,
                              hipStream_t stream) {
    const float* x  = (const float*)d_in[0];
    const int*   ei = (const int*)d_in[1];     // [2][N_EDGES]: src row then dst row
    // d_in[2] = batch (unused)
    const float* W1 = (const float*)d_in[3];
    const float* b1 = (const float*)d_in[4];
    const float* W2 = (const float*)d_in[5];
    const float* b2 = (const float*)d_in[6];
    float* out = (float*)d_out;

    const int* src = ei;
    const int* dst = ei + N_EDGES;

    // workspace layout: one ping-pong float buffer (d_out is the other),
    // then the CSR/scan int arrays. Total ≈ 25.6 MB + 3.8 MB.
    float* bufA = (float*)d_ws;                         // N_NODES*DIM floats
    int*   cnt  = (int*)(bufA + (size_t)N_NODES * DIM); // N_NODES
    int*   offs = cnt + N_NODES;                        // N_NODES+1
    int*   cur  = offs + N_NODES + 1;                   // N_NODES
    int*   bsum = cur + N_NODES;                        // 256
    int*   csr  = bsum + 256;                           // N_EDGES

    // --- build CSR (dst -> srcs) once per call ---
    zero_kernel<<<NB, 256, 0, stream>>>(cnt, N_NODES);
    count_kernel<<<(N_EDGES + 255) / 256, 256, 0, stream>>>(dst, cnt);
    scanA<<<NB, SCAN_BLK, 0, stream>>>(cnt, offs, bsum);
    scanB<<<1, SCAN_BLK, 0, stream>>>(bsum);
    scanC<<<NB, SCAN_BLK, 0, stream>>>(offs, bsum, cur);
    scatter_kernel<<<(N_EDGES + 255) / 256, 256, 0, stream>>>(src, dst, cur, csr);

    const int nblk = (N_NODES + RT - 1) / RT;
    // layer 0: x -> bufA
    gin_layer<<<nblk, 256, 0, stream>>>(x,    offs, csr, W1 + 0 * DIM * DIM, b1 + 0 * DIM,
                                        W2 + 0 * DIM * DIM, b2 + 0 * DIM, bufA);
    // layer 1: bufA -> out (d_out doubles as ping-pong buffer)
    gin_layer<<<nblk, 256, 0, stream>>>(bufA, offs, csr, W1 + 1 * DIM * DIM, b1 + 1 * DIM,
                                        W2 + 1 * DIM * DIM, b2 + 1 * DIM, out);
    // layer 2: out -> bufA
    gin_layer<<<nblk, 256, 0, stream>>>(out,  offs, csr, W1 + 2 * DIM * DIM, b1 + 2 * DIM,
                                        W2 + 2 * DIM * DIM, b2 + 2 * DIM, bufA);
    // layer 3: bufA -> out
    gin_layer<<<nblk, 256, 0, stream>>>(bufA, offs, csr, W1 + 3 * DIM * DIM, b1 + 3 * DIM,
                                        W2 + 3 * DIM * DIM, b2 + 3 * DIM, out);
}